// Round 3
// baseline (458.416 us; speedup 1.0000x reference)
//
#include <hip/hip_runtime.h>
#include <cstdint>

#define N_TOK 4096
#define DIM   1024
#define NEXP  8
#define FDIM  2048

typedef _Float16 f16_t;
typedef _Float16 f16x8 __attribute__((ext_vector_type(8)));
typedef float    f32x4 __attribute__((ext_vector_type(4)));

__device__ inline unsigned packh(float a, float b) {
    union { f16_t h[2]; unsigned u; } p;
    p.h[0] = (f16_t)a; p.h[1] = (f16_t)b;
    return p.u;
}

// async global->LDS, 16B per lane; LDS dest must be base + lane*16 (it is, by construction)
__device__ inline void gl2lds16(const void* g, void* l) {
    __builtin_amdgcn_global_load_lds(
        (const __attribute__((address_space(1))) unsigned*)g,
        (__attribute__((address_space(3))) unsigned*)l, 16, 0, 0);
}

template<int N>
__device__ inline void vmw() {
    asm volatile("s_waitcnt vmcnt(%0)" :: "i"(N) : "memory");
}

// ---------------- Router (+ fused x->f16 cast): logits -> softmax -> top2 -> scatter ----------------
__global__ __launch_bounds__(256) void router_kernel(
    const float* __restrict__ x, const float* __restrict__ wr,
    float* __restrict__ topw, int* __restrict__ counts, int* __restrict__ bucket,
    f16_t* __restrict__ xf)
{
    __shared__ float r[NEXP][DIM];   // router transposed, 32 KB
    __shared__ int sIdx[32];         // per-block top2 expert ids, 2 per token
    int tid = threadIdx.x;

    // fused cast: this block's 16 tokens, fp32 -> f16 (x slab is L2-hot, router re-reads it)
    {
        const float* xblk = x + (size_t)blockIdx.x * 16 * DIM;
        f16_t* xfblk = xf + (size_t)blockIdx.x * 16 * DIM;
#pragma unroll
        for (int i = tid; i < 16 * DIM / 8; i += 256) {
            float4 a = ((const float4*)xblk)[2 * i];
            float4 b = ((const float4*)xblk)[2 * i + 1];
            union { f16_t h[8]; uint4 u; } pk;
            pk.h[0] = (f16_t)a.x; pk.h[1] = (f16_t)a.y; pk.h[2] = (f16_t)a.z; pk.h[3] = (f16_t)a.w;
            pk.h[4] = (f16_t)b.x; pk.h[5] = (f16_t)b.y; pk.h[6] = (f16_t)b.z; pk.h[7] = (f16_t)b.w;
            ((uint4*)xfblk)[i] = pk.u;
        }
    }

    for (int i = tid; i < DIM * NEXP / 4; i += 256) {
        float4 v = ((const float4*)wr)[i];
        int base = i * 4;                    // flat = d*8 + e
        r[(base + 0) & 7][(base + 0) >> 3] = v.x;
        r[(base + 1) & 7][(base + 1) >> 3] = v.y;
        r[(base + 2) & 7][(base + 2) >> 3] = v.z;
        r[(base + 3) & 7][(base + 3) >> 3] = v.w;
    }
    __syncthreads();
    int wave = tid >> 6, lane = tid & 63;
    int t0 = blockIdx.x * 16 + wave * 4;
    for (int tt = 0; tt < 4; ++tt) {
        int t = t0 + tt;
        float acc[NEXP];
#pragma unroll
        for (int e = 0; e < NEXP; e++) acc[e] = 0.f;
        const float* xr = x + (size_t)t * DIM;
#pragma unroll
        for (int k = 0; k < DIM / 64; k++) {
            int d = lane + k * 64;
            float xv = xr[d];
#pragma unroll
            for (int e = 0; e < NEXP; e++) acc[e] += xv * r[e][d];
        }
#pragma unroll
        for (int e = 0; e < NEXP; e++) {
#pragma unroll
            for (int off = 32; off > 0; off >>= 1)
                acc[e] += __shfl_xor(acc[e], off, 64);
        }
        if (lane == 0) {
            float mx = acc[0];
#pragma unroll
            for (int e = 1; e < NEXP; e++) mx = fmaxf(mx, acc[e]);
            float p[NEXP]; float s = 0.f;
#pragma unroll
            for (int e = 0; e < NEXP; e++) { p[e] = expf(acc[e] - mx); s += p[e]; }
            float inv = 1.f / s;
#pragma unroll
            for (int e = 0; e < NEXP; e++) p[e] *= inv;
            int i1 = 0; float p1 = p[0];
#pragma unroll
            for (int e = 1; e < NEXP; e++) if (p[e] > p1) { p1 = p[e]; i1 = e; }
            int i2 = -1; float p2 = -1.f;
#pragma unroll
            for (int e = 0; e < NEXP; e++) if (e != i1 && p[e] > p2) { p2 = p[e]; i2 = e; }
            float e2 = expf(p2 - p1);          // softmax over top-2 probs
            float w1 = 1.f / (1.f + e2);
            topw[t * 2 + 0] = w1;
            topw[t * 2 + 1] = e2 * w1;
            int j = (wave * 4 + tt) * 2;
            sIdx[j + 0] = i1;
            sIdx[j + 1] = i2;
        }
    }
    __syncthreads();
    if (tid < NEXP) {
        int cnt = 0;
#pragma unroll
        for (int j = 0; j < 32; j++) cnt += (sIdx[j] == tid) ? 1 : 0;
        if (cnt > 0) {
            int pos = atomicAdd(&counts[tid * 32], cnt);
#pragma unroll
            for (int j = 0; j < 32; j++)
                if (sIdx[j] == tid)
                    bucket[tid * N_TOK + pos++] = (blockIdx.x * 16 + (j >> 1)) * 2 + (j & 1);
        }
    }
}

// ---------------- Weight transpose+convert: in [R][C] fp32 -> out [C][R] f16 ----------------
__global__ __launch_bounds__(256) void transpose_cvt(
    const float* __restrict__ inA, const float* __restrict__ inB,
    f16_t* __restrict__ outA, f16_t* __restrict__ outB,
    int R, int C, int tiles_r, int nA)
{
    __shared__ unsigned sP[64][68];
    int m = blockIdx.y;
    const float* in; f16_t* out;
    if (m < nA) { in = inA + (size_t)m * DIM * FDIM; out = outA + (size_t)m * DIM * FDIM; }
    else        { in = inB + (size_t)(m - nA) * DIM * FDIM; out = outB + (size_t)(m - nA) * DIM * FDIM; }
    int tix = blockIdx.x;
    int rb = (tix % tiles_r) * 128;
    int cb = (tix / tiles_r) * 64;
    int t = threadIdx.x;
    int dp = t >> 2;
    int fc = (t & 3) * 16;
    const float* r0 = in + (size_t)(rb + 2 * dp) * C + cb + fc;
    const float* r1 = r0 + C;
#pragma unroll
    for (int j = 0; j < 16; j += 4) {
        float4 a = *(const float4*)(r0 + j);
        float4 b = *(const float4*)(r1 + j);
        sP[fc + j + 0][dp] = packh(a.x, b.x);
        sP[fc + j + 1][dp] = packh(a.y, b.y);
        sP[fc + j + 2][dp] = packh(a.z, b.z);
        sP[fc + j + 3][dp] = packh(a.w, b.w);
    }
    __syncthreads();
    int c = t >> 2;
    int rc = t & 3;
    uint4* dst = (uint4*)(out + (size_t)(cb + c) * R + rb + rc * 32);
    const unsigned* src = &sP[c][rc * 16];
#pragma unroll
    for (int j = 0; j < 4; j++)
        dst[j] = *(const uint4*)(src + j * 4);
}

// ---------------- Stage A: H = silu(x@Wg) * (x@Wu) ----------------
// Round-0 geometry (128m x 64f x {G,U}, 4 waves, BK=32, small tiles -> ~2100 items,
// 3 blocks/CU) upgraded with ring-3 LDS + stage-2-ahead counted vmcnt (T3/T4):
//   body t: STG(buf (t+2)%3, k=t+2)  [WAR-safe: its readers drained before barrier t-1]
//           ds_read+MFMA on buf t%3  [ready: all waves passed vmw<4>+barrier at t-1]
//           vmw<4> [retires t+1's 4 loads, issued 2 bodies ago; keeps t+2's in flight]
//           s_barrier (raw; no vmcnt(0) drain in steady state)
#define GU_STG(B, KO)                                                           \
    gl2lds16(gA0 + (KO), lA0 + (B) * 4096);                                     \
    gl2lds16(gA1 + (KO), lA1 + (B) * 4096);                                     \
    gl2lds16(gBg + (KO), lBg + (B) * 2048);                                     \
    gl2lds16(gBu + (KO), lBu + (B) * 2048);

#define GU_COMPUTE(RB)                                                          \
    {                                                                           \
        f16x8 af[4], bg[2], bu[2];                                              \
        _Pragma("unroll")                                                       \
        for (int mi = 0; mi < 4; mi++)                                          \
            af[mi] = *(const f16x8*)&sA[(RB) * 4096 + (wm + mi * 16 + fm) * 32 + p8]; \
        _Pragma("unroll")                                                       \
        for (int ni = 0; ni < 2; ni++) {                                        \
            bg[ni] = *(const f16x8*)&sBg[(RB) * 2048 + (wn + ni * 16 + fm) * 32 + p8]; \
            bu[ni] = *(const f16x8*)&sBu[(RB) * 2048 + (wn + ni * 16 + fm) * 32 + p8]; \
        }                                                                       \
        __builtin_amdgcn_s_setprio(1);                                          \
        _Pragma("unroll")                                                       \
        for (int mi = 0; mi < 4; mi++)                                          \
            _Pragma("unroll")                                                   \
            for (int ni = 0; ni < 2; ni++) {                                    \
                accG[mi][ni] = __builtin_amdgcn_mfma_f32_16x16x32_f16(af[mi], bg[ni], accG[mi][ni], 0, 0, 0); \
                accU[mi][ni] = __builtin_amdgcn_mfma_f32_16x16x32_f16(af[mi], bu[ni], accU[mi][ni], 0, 0, 0); \
            }                                                                   \
        __builtin_amdgcn_s_setprio(0);                                          \
    }

__global__ __launch_bounds__(256) void gateup_kernel(
    const f16_t* __restrict__ xf,
    const f16_t* __restrict__ wgT, const f16_t* __restrict__ wuT,
    const int* __restrict__ counts, const int* __restrict__ bucket,
    f16_t* __restrict__ H)
{
    int e = blockIdx.z;
    int cnt = counts[e * 32];
    int m0 = blockIdx.y * 128;
    if (m0 >= cnt) return;
    int n0 = blockIdx.x * 64;

    __shared__ f16_t sA[3 * 128 * 32];    // 24 KB, ring-3
    __shared__ f16_t sBg[3 * 64 * 32];    // 12 KB
    __shared__ f16_t sBu[3 * 64 * 32];    // 12 KB
    __shared__ int sEnt[128];

    int tid = threadIdx.x;
    if (tid < 128) {
        int i = m0 + tid;
        sEnt[tid] = bucket[e * N_TOK + (i < cnt ? i : m0)];
    }
    __syncthreads();

    int wave = tid >> 6, lane = tid & 63;
    int q = ((lane & 3) - (lane >> 3)) & 3;     // global-side chunk swizzle
    int rA0 = wave * 32 + (lane >> 2);
    int rA1 = rA0 + 16;
    int rB  = wave * 16 + (lane >> 2);
    const f16_t* gA0 = xf + (size_t)(sEnt[rA0] >> 1) * DIM + q * 8;
    const f16_t* gA1 = xf + (size_t)(sEnt[rA1] >> 1) * DIM + q * 8;
    const f16_t* gBg = wgT + ((size_t)e * FDIM + n0 + rB) * DIM + q * 8;
    const f16_t* gBu = wuT + ((size_t)e * FDIM + n0 + rB) * DIM + q * 8;
    f16_t* lA0 = &sA[wave * 1024 + lane * 8];
    f16_t* lA1 = lA0 + 512;
    f16_t* lBg = &sBg[wave * 512 + lane * 8];
    f16_t* lBu = &sBu[wave * 512 + lane * 8];

    f32x4 accG[4][2], accU[4][2];
    f32x4 zero = {0.f, 0.f, 0.f, 0.f};
#pragma unroll
    for (int i = 0; i < 4; i++)
#pragma unroll
        for (int j = 0; j < 2; j++) { accG[i][j] = zero; accU[i][j] = zero; }

    int wm = (wave & 1) * 64, wn = (wave >> 1) * 32;
    int fm = lane & 15, quad = lane >> 4;
    int p8 = ((quad + (fm >> 1)) & 3) * 8;      // swizzled chunk offset for frag reads

    // prologue: stage k-tiles 0,1
    GU_STG(0, 0);
    GU_STG(1, 32);
    vmw<4>();                          // own k0 loads landed
    __builtin_amdgcn_s_barrier();      // everyone's k0 loads landed

    int rb3 = 0, sb3 = 2;
    for (int t = 0; t < 30; ++t) {
        GU_STG(sb3, (t + 2) * 32);
        GU_COMPUTE(rb3);
        vmw<4>();
        __builtin_amdgcn_s_barrier();
        rb3 = (rb3 == 2) ? 0 : rb3 + 1;
        sb3 = (sb3 == 2) ? 0 : sb3 + 1;
    }
    // tail: t=30 (k-tile 31 already staged; drain it)
    GU_COMPUTE(rb3);
    vmw<0>();
    __builtin_amdgcn_s_barrier();
    rb3 = (rb3 == 2) ? 0 : rb3 + 1;
    // t=31
    GU_COMPUTE(rb3);

    // epilogue: silu(G)*U -> H. C/D layout: col=lane&15, row=(lane>>4)*4+i
    int crow = quad * 4, ccol = fm;
#pragma unroll
    for (int mi = 0; mi < 4; mi++) {
#pragma unroll
        for (int i = 0; i < 4; i++) {
            int m = wm + mi * 16 + crow + i;
            if (m0 + m < cnt) {
                int ent = sEnt[m];
                f16_t* hr = H + (size_t)ent * FDIM + n0 + wn;
#pragma unroll
                for (int ni = 0; ni < 2; ni++) {
                    float g = accG[mi][ni][i], u = accU[mi][ni][i];
                    float h = (g / (1.f + __expf(-g))) * u;
                    hr[ni * 16 + ccol] = (f16_t)h;
                }
            }
        }
    }
}

// ---------------- Stage B: Y[ent,d] = w[ent] * (H[ent,:] @ Wd); 128x128, ring-3 counted ----------------
#define DN_STG(B, KO)                                                           \
    gl2lds16(gA0 + (KO), lA0 + (B) * 4096);                                     \
    gl2lds16(gA1 + (KO), lA1 + (B) * 4096);                                     \
    gl2lds16(gB0 + (KO), lB0 + (B) * 4096);                                     \
    gl2lds16(gB1 + (KO), lB1 + (B) * 4096);

#define DN_COMPUTE(RB)                                                          \
    {                                                                           \
        f16x8 af[4], bf[4];                                                     \
        _Pragma("unroll")                                                       \
        for (int mi = 0; mi < 4; mi++)                                          \
            af[mi] = *(const f16x8*)&sA[(RB) * 4096 + (wm + mi * 16 + fm) * 32 + p8]; \
        _Pragma("unroll")                                                       \
        for (int ni = 0; ni < 4; ni++)                                          \
            bf[ni] = *(const f16x8*)&sB[(RB) * 4096 + (wn + ni * 16 + fm) * 32 + p8]; \
        __builtin_amdgcn_s_setprio(1);                                          \
        _Pragma("unroll")                                                       \
        for (int mi = 0; mi < 4; mi++)                                          \
            _Pragma("unroll")                                                   \
            for (int ni = 0; ni < 4; ni++)                                      \
                acc[mi][ni] = __builtin_amdgcn_mfma_f32_16x16x32_f16(af[mi], bf[ni], acc[mi][ni], 0, 0, 0); \
        __builtin_amdgcn_s_setprio(0);                                          \
    }

__global__ __launch_bounds__(256) void down_kernel(
    const f16_t* __restrict__ H, const f16_t* __restrict__ wdT,
    const int* __restrict__ counts, const int* __restrict__ bucket,
    const float* __restrict__ topw, float* __restrict__ Y)
{
    int e = blockIdx.z;
    int cnt = counts[e * 32];
    int m0 = blockIdx.y * 128;
    if (m0 >= cnt) return;
    int n0 = blockIdx.x * 128;

    __shared__ f16_t sA[3 * 128 * 32];    // 24 KB, ring-3
    __shared__ f16_t sB[3 * 128 * 32];    // 24 KB
    __shared__ int sEnt[128];

    int tid = threadIdx.x;
    if (tid < 128) {
        int i = m0 + tid;
        sEnt[tid] = bucket[e * N_TOK + (i < cnt ? i : m0)];
    }
    __syncthreads();

    int wave = tid >> 6, lane = tid & 63;
    int q = ((lane & 3) - (lane >> 3)) & 3;
    int r0 = wave * 32 + (lane >> 2);
    int r1 = r0 + 16;
    const f16_t* gA0 = H + (size_t)sEnt[r0] * FDIM + q * 8;
    const f16_t* gA1 = H + (size_t)sEnt[r1] * FDIM + q * 8;
    const f16_t* gB0 = wdT + ((size_t)e * DIM + n0 + r0) * FDIM + q * 8;
    const f16_t* gB1 = wdT + ((size_t)e * DIM + n0 + r1) * FDIM + q * 8;
    f16_t* lA0 = &sA[wave * 1024 + lane * 8];
    f16_t* lA1 = lA0 + 512;
    f16_t* lB0 = &sB[wave * 1024 + lane * 8];
    f16_t* lB1 = lB0 + 512;

    f32x4 acc[4][4];
    f32x4 zero = {0.f, 0.f, 0.f, 0.f};
#pragma unroll
    for (int i = 0; i < 4; i++)
#pragma unroll
        for (int j = 0; j < 4; j++) acc[i][j] = zero;

    int wm = (wave & 1) * 64, wn = (wave >> 1) * 64;
    int fm = lane & 15, quad = lane >> 4;
    int p8 = ((quad + (fm >> 1)) & 3) * 8;

    // prologue: stage k-tiles 0,1
    DN_STG(0, 0);
    DN_STG(1, 32);
    vmw<4>();
    __builtin_amdgcn_s_barrier();

    int rb3 = 0, sb3 = 2;
    for (int t = 0; t < 62; ++t) {            // FDIM/32 = 64 k-tiles
        DN_STG(sb3, (t + 2) * 32);
        DN_COMPUTE(rb3);
        vmw<4>();
        __builtin_amdgcn_s_barrier();
        rb3 = (rb3 == 2) ? 0 : rb3 + 1;
        sb3 = (sb3 == 2) ? 0 : sb3 + 1;
    }
    DN_COMPUTE(rb3);
    vmw<0>();
    __builtin_amdgcn_s_barrier();
    rb3 = (rb3 == 2) ? 0 : rb3 + 1;
    DN_COMPUTE(rb3);

    int crow = quad * 4, ccol = fm;
#pragma unroll
    for (int mi = 0; mi < 4; mi++) {
#pragma unroll
        for (int i = 0; i < 4; i++) {
            int m = wm + mi * 16 + crow + i;
            if (m0 + m < cnt) {
                int ent = sEnt[m];
                float w = topw[ent];
                float* yr = Y + (size_t)ent * DIM + n0 + wn;
#pragma unroll
                for (int ni = 0; ni < 4; ni++)
                    yr[ni * 16 + ccol] = w * acc[mi][ni][i];
            }
        }
    }
}

// ---------------- Combine: out[t] = Y[2t] + Y[2t+1] ----------------
__global__ __launch_bounds__(256) void combine_kernel(
    const float* __restrict__ Y, float* __restrict__ out)
{
    int i = blockIdx.x * 256 + threadIdx.x;
    int t = i >> 8;
    int c = i & 255;
    float4 a = ((const float4*)Y)[(size_t)(2 * t) * 256 + c];
    float4 b = ((const float4*)Y)[(size_t)(2 * t + 1) * 256 + c];
    float4 o;
    o.x = a.x + b.x; o.y = a.y + b.y; o.z = a.z + b.z; o.w = a.w + b.w;
    ((float4*)out)[i] = o;
}

extern "C" void kernel_launch(void* const* d_in, const int* in_sizes, int n_in,
                              void* d_out, int out_size, void* d_ws, size_t ws_size,
                              hipStream_t stream) {
    const float* x  = (const float*)d_in[0];
    const float* wr = (const float*)d_in[1];
    const float* wg = (const float*)d_in[2];
    const float* wu = (const float*)d_in[3];
    const float* wd = (const float*)d_in[4];
    float* out = (float*)d_out;
    char* ws = (char*)d_ws;
    const size_t MB = 1ull << 20;

    int*   counts = (int*)ws;                       // 1 KB
    int*   bucket = (int*)(ws + 1024);              // 128 KB
    float* topw   = (float*)(ws + 160 * 1024);      // 32 KB
    f16_t* xf     = (f16_t*)(ws + 1 * MB);          // 1..9 MB   (dead after gateup)
    f16_t* wgT    = (f16_t*)(ws + 9 * MB);          // 9..41 MB  (dead after gateup)
    f16_t* wuT    = (f16_t*)(ws + 41 * MB);         // 41..73 MB (dead after gateup)
    f16_t* H      = (f16_t*)(ws + 73 * MB);         // 73..105 MB
    f16_t* wdT    = (f16_t*)(ws + 1 * MB);          // alias 1..33 MB
    float* Y      = (float*)(ws + 33 * MB);         // alias 33..65 MB

    hipMemsetAsync(counts, 0, 1024, stream);
    router_kernel<<<256, 256, 0, stream>>>(x, wr, topw, counts, bucket, xf);
    transpose_cvt<<<dim3(256, 16), 256, 0, stream>>>(wg, wu, wgT, wuT, DIM, FDIM, DIM / 128, NEXP);
    gateup_kernel<<<dim3(FDIM / 64, 32, NEXP), 256, 0, stream>>>(xf, wgT, wuT, counts, bucket, H);
    transpose_cvt<<<dim3(256, 8), 256, 0, stream>>>(wd, wd, wdT, wdT, FDIM, DIM, FDIM / 128, NEXP);
    down_kernel<<<dim3(DIM / 128, 32, NEXP), 256, 0, stream>>>(H, wdT, counts, bucket, topw, Y);
    combine_kernel<<<4096, 256, 0, stream>>>(Y, out);
}

// Round 4
// 428.298 us; speedup vs baseline: 1.0703x; 1.0703x over previous
//
#include <hip/hip_runtime.h>
#include <cstdint>

#define N_TOK 4096
#define DIM   1024
#define NEXP  8
#define FDIM  2048

typedef _Float16 f16_t;
typedef _Float16 f16x8 __attribute__((ext_vector_type(8)));
typedef float    f32x4 __attribute__((ext_vector_type(4)));

__device__ inline unsigned packh(float a, float b) {
    union { f16_t h[2]; unsigned u; } p;
    p.h[0] = (f16_t)a; p.h[1] = (f16_t)b;
    return p.u;
}

// async global->LDS, 16B per lane; LDS dest must be base + lane*16 (it is, by construction)
__device__ inline void gl2lds16(const void* g, void* l) {
    __builtin_amdgcn_global_load_lds(
        (const __attribute__((address_space(1))) unsigned*)g,
        (__attribute__((address_space(3))) unsigned*)l, 16, 0, 0);
}

// ---------------- Router (+ fused x->f16 cast): logits -> softmax -> top2 -> scatter ----------------
__global__ __launch_bounds__(256) void router_kernel(
    const float* __restrict__ x, const float* __restrict__ wr,
    float* __restrict__ topw, int* __restrict__ counts, int* __restrict__ bucket,
    f16_t* __restrict__ xf)
{
    __shared__ float r[NEXP][DIM];   // router transposed, 32 KB
    __shared__ int sIdx[32];         // per-block top2 expert ids, 2 per token
    int tid = threadIdx.x;

    // fused cast: this block's 16 tokens, fp32 -> f16 (x slab is L2-hot, router re-reads it)
    {
        const float* xblk = x + (size_t)blockIdx.x * 16 * DIM;
        f16_t* xfblk = xf + (size_t)blockIdx.x * 16 * DIM;
#pragma unroll
        for (int i = tid; i < 16 * DIM / 8; i += 256) {
            float4 a = ((const float4*)xblk)[2 * i];
            float4 b = ((const float4*)xblk)[2 * i + 1];
            union { f16_t h[8]; uint4 u; } pk;
            pk.h[0] = (f16_t)a.x; pk.h[1] = (f16_t)a.y; pk.h[2] = (f16_t)a.z; pk.h[3] = (f16_t)a.w;
            pk.h[4] = (f16_t)b.x; pk.h[5] = (f16_t)b.y; pk.h[6] = (f16_t)b.z; pk.h[7] = (f16_t)b.w;
            ((uint4*)xfblk)[i] = pk.u;
        }
    }

    for (int i = tid; i < DIM * NEXP / 4; i += 256) {
        float4 v = ((const float4*)wr)[i];
        int base = i * 4;                    // flat = d*8 + e
        r[(base + 0) & 7][(base + 0) >> 3] = v.x;
        r[(base + 1) & 7][(base + 1) >> 3] = v.y;
        r[(base + 2) & 7][(base + 2) >> 3] = v.z;
        r[(base + 3) & 7][(base + 3) >> 3] = v.w;
    }
    __syncthreads();
    int wave = tid >> 6, lane = tid & 63;
    int t0 = blockIdx.x * 16 + wave * 4;
    for (int tt = 0; tt < 4; ++tt) {
        int t = t0 + tt;
        float acc[NEXP];
#pragma unroll
        for (int e = 0; e < NEXP; e++) acc[e] = 0.f;
        const float* xr = x + (size_t)t * DIM;
#pragma unroll
        for (int k = 0; k < DIM / 64; k++) {
            int d = lane + k * 64;
            float xv = xr[d];
#pragma unroll
            for (int e = 0; e < NEXP; e++) acc[e] += xv * r[e][d];
        }
#pragma unroll
        for (int e = 0; e < NEXP; e++) {
#pragma unroll
            for (int off = 32; off > 0; off >>= 1)
                acc[e] += __shfl_xor(acc[e], off, 64);
        }
        if (lane == 0) {
            float mx = acc[0];
#pragma unroll
            for (int e = 1; e < NEXP; e++) mx = fmaxf(mx, acc[e]);
            float p[NEXP]; float s = 0.f;
#pragma unroll
            for (int e = 0; e < NEXP; e++) { p[e] = expf(acc[e] - mx); s += p[e]; }
            float inv = 1.f / s;
#pragma unroll
            for (int e = 0; e < NEXP; e++) p[e] *= inv;
            int i1 = 0; float p1 = p[0];
#pragma unroll
            for (int e = 1; e < NEXP; e++) if (p[e] > p1) { p1 = p[e]; i1 = e; }
            int i2 = -1; float p2 = -1.f;
#pragma unroll
            for (int e = 0; e < NEXP; e++) if (e != i1 && p[e] > p2) { p2 = p[e]; i2 = e; }
            float e2 = expf(p2 - p1);          // softmax over top-2 probs
            float w1 = 1.f / (1.f + e2);
            topw[t * 2 + 0] = w1;
            topw[t * 2 + 1] = e2 * w1;
            int j = (wave * 4 + tt) * 2;
            sIdx[j + 0] = i1;
            sIdx[j + 1] = i2;
        }
    }
    __syncthreads();
    if (tid < NEXP) {
        int cnt = 0;
#pragma unroll
        for (int j = 0; j < 32; j++) cnt += (sIdx[j] == tid) ? 1 : 0;
        if (cnt > 0) {
            int pos = atomicAdd(&counts[tid * 32], cnt);
#pragma unroll
            for (int j = 0; j < 32; j++)
                if (sIdx[j] == tid)
                    bucket[tid * N_TOK + pos++] = (blockIdx.x * 16 + (j >> 1)) * 2 + (j & 1);
        }
    }
}

// ---------------- Weight transpose+convert: in [R][C] fp32 -> out [C][R] f16 ----------------
__global__ __launch_bounds__(256) void transpose_cvt(
    const float* __restrict__ inA, const float* __restrict__ inB,
    f16_t* __restrict__ outA, f16_t* __restrict__ outB,
    int R, int C, int tiles_r, int nA)
{
    __shared__ unsigned sP[64][68];
    int m = blockIdx.y;
    const float* in; f16_t* out;
    if (m < nA) { in = inA + (size_t)m * DIM * FDIM; out = outA + (size_t)m * DIM * FDIM; }
    else        { in = inB + (size_t)(m - nA) * DIM * FDIM; out = outB + (size_t)(m - nA) * DIM * FDIM; }
    int tix = blockIdx.x;
    int rb = (tix % tiles_r) * 128;
    int cb = (tix / tiles_r) * 64;
    int t = threadIdx.x;
    int dp = t >> 2;
    int fc = (t & 3) * 16;
    const float* r0 = in + (size_t)(rb + 2 * dp) * C + cb + fc;
    const float* r1 = r0 + C;
#pragma unroll
    for (int j = 0; j < 16; j += 4) {
        float4 a = *(const float4*)(r0 + j);
        float4 b = *(const float4*)(r1 + j);
        sP[fc + j + 0][dp] = packh(a.x, b.x);
        sP[fc + j + 1][dp] = packh(a.y, b.y);
        sP[fc + j + 2][dp] = packh(a.z, b.z);
        sP[fc + j + 3][dp] = packh(a.w, b.w);
    }
    __syncthreads();
    int c = t >> 2;
    int rc = t & 3;
    uint4* dst = (uint4*)(out + (size_t)(cb + c) * R + rb + rc * 32);
    const unsigned* src = &sP[c][rc * 16];
#pragma unroll
    for (int j = 0; j < 4; j++)
        dst[j] = *(const uint4*)(src + j * 4);
}

// ---------------- Stage A: H = silu(x@Wg) * (x@Wu) ----------------
// Round-0 2-phase structure (proven fastest: multi-block overlap hides drains),
// with BK 32->64: 32 MFMA per barrier-drain instead of 16, halving the stall
// fraction. LDS 33 KB -> still 4 blocks/CU by LDS.
// Rows are 64 f16 = 8 chunks of 16B; rotation swizzle phys=(logical+row)&7:
// - staging: dest chunk g = j*256+tid -> row g>>3, phys tid&7; source logical
//   c = ((tid&7)-(tid>>3))&7 (same for all j since rows step by 32).
// - frag read: logical = ks*4+quad -> phys = (ks*4+quad+fm)&7; each
//   consecutive-8-lane octet has fixed quad + fm spanning 8 values -> 8
//   distinct 16B bank-groups -> conflict-free.
__global__ __launch_bounds__(256) void gateup_kernel(
    const f16_t* __restrict__ xf,
    const f16_t* __restrict__ wgT, const f16_t* __restrict__ wuT,
    const int* __restrict__ counts, const int* __restrict__ bucket,
    f16_t* __restrict__ H)
{
    int e = blockIdx.z;
    int cnt = counts[e * 32];
    int m0 = blockIdx.y * 128;
    if (m0 >= cnt) return;
    int n0 = blockIdx.x * 64;

    __shared__ f16_t sA[128 * 64];    // 16 KB
    __shared__ f16_t sBg[64 * 64];    // 8 KB
    __shared__ f16_t sBu[64 * 64];    // 8 KB
    __shared__ int sEnt[128];

    int tid = threadIdx.x;
    if (tid < 128) {
        int i = m0 + tid;
        sEnt[tid] = bucket[e * N_TOK + (i < cnt ? i : m0)];
    }
    __syncthreads();

    int wave = tid >> 6, lane = tid & 63;
    int c8 = (((tid & 7) - (tid >> 3)) & 7) * 8;   // source k-chunk (f16 units)
    int ra = tid >> 3;                              // base row 0..31

    const f16_t* gA[4];
#pragma unroll
    for (int j = 0; j < 4; j++)
        gA[j] = xf + (size_t)(sEnt[ra + j * 32] >> 1) * DIM + c8;
    const f16_t* gBg0 = wgT + ((size_t)e * FDIM + n0 + ra) * DIM + c8;
    const f16_t* gBu0 = wuT + ((size_t)e * FDIM + n0 + ra) * DIM + c8;
    f16_t* dA  = &sA[tid * 8];
    f16_t* dBg = &sBg[tid * 8];
    f16_t* dBu = &sBu[tid * 8];

    f32x4 accG[4][2], accU[4][2];
    f32x4 zero = {0.f, 0.f, 0.f, 0.f};
#pragma unroll
    for (int i = 0; i < 4; i++)
#pragma unroll
        for (int j = 0; j < 2; j++) { accG[i][j] = zero; accU[i][j] = zero; }

    int wm = (wave & 1) * 64, wn = (wave >> 1) * 32;
    int fm = lane & 15, quad = lane >> 4;

    for (int k0 = 0; k0 < DIM; k0 += 64) {
#pragma unroll
        for (int j = 0; j < 4; j++)
            gl2lds16(gA[j] + k0, dA + j * 2048);
        gl2lds16(gBg0 + k0, dBg);
        gl2lds16(gBg0 + 32 * DIM + k0, dBg + 2048);
        gl2lds16(gBu0 + k0, dBu);
        gl2lds16(gBu0 + 32 * DIM + k0, dBu + 2048);
        __syncthreads();
#pragma unroll
        for (int ks = 0; ks < 2; ++ks) {
            f16x8 af[4], bg[2], bu[2];
#pragma unroll
            for (int mi = 0; mi < 4; mi++)
                af[mi] = *(const f16x8*)&sA[(wm + mi * 16 + fm) * 64 +
                                            ((ks * 4 + quad + fm) & 7) * 8];
#pragma unroll
            for (int ni = 0; ni < 2; ni++) {
                bg[ni] = *(const f16x8*)&sBg[(wn + ni * 16 + fm) * 64 +
                                              ((ks * 4 + quad + fm) & 7) * 8];
                bu[ni] = *(const f16x8*)&sBu[(wn + ni * 16 + fm) * 64 +
                                              ((ks * 4 + quad + fm) & 7) * 8];
            }
#pragma unroll
            for (int mi = 0; mi < 4; mi++)
#pragma unroll
                for (int ni = 0; ni < 2; ni++) {
                    accG[mi][ni] = __builtin_amdgcn_mfma_f32_16x16x32_f16(af[mi], bg[ni], accG[mi][ni], 0, 0, 0);
                    accU[mi][ni] = __builtin_amdgcn_mfma_f32_16x16x32_f16(af[mi], bu[ni], accU[mi][ni], 0, 0, 0);
                }
        }
        __syncthreads();
    }
    // epilogue: silu(G)*U -> H. C/D layout: col=lane&15, row=(lane>>4)*4+i
    int crow = quad * 4, ccol = fm;
#pragma unroll
    for (int mi = 0; mi < 4; mi++) {
#pragma unroll
        for (int i = 0; i < 4; i++) {
            int m = wm + mi * 16 + crow + i;
            if (m0 + m < cnt) {
                int ent = sEnt[m];
                f16_t* hr = H + (size_t)ent * FDIM + n0 + wn;
#pragma unroll
                for (int ni = 0; ni < 2; ni++) {
                    float g = accG[mi][ni][i], u = accU[mi][ni][i];
                    float h = (g / (1.f + __expf(-g))) * u;
                    hr[ni * 16 + ccol] = (f16_t)h;
                }
            }
        }
    }
}

// ---------------- Stage B: Y[ent,d] = w[ent] * (H[ent,:] @ Wd); 128x128, BK=64 ----------------
__global__ __launch_bounds__(256) void down_kernel(
    const f16_t* __restrict__ H, const f16_t* __restrict__ wdT,
    const int* __restrict__ counts, const int* __restrict__ bucket,
    const float* __restrict__ topw, float* __restrict__ Y)
{
    int e = blockIdx.z;
    int cnt = counts[e * 32];
    int m0 = blockIdx.y * 128;
    if (m0 >= cnt) return;
    int n0 = blockIdx.x * 128;

    __shared__ f16_t sA[128 * 64];    // 16 KB
    __shared__ f16_t sB[128 * 64];    // 16 KB
    __shared__ int sEnt[128];

    int tid = threadIdx.x;
    if (tid < 128) {
        int i = m0 + tid;
        sEnt[tid] = bucket[e * N_TOK + (i < cnt ? i : m0)];
    }
    __syncthreads();

    int wave = tid >> 6, lane = tid & 63;
    int c8 = (((tid & 7) - (tid >> 3)) & 7) * 8;
    int ra = tid >> 3;

    const f16_t* gA[4];
    const f16_t* gB[4];
#pragma unroll
    for (int j = 0; j < 4; j++) {
        gA[j] = H + (size_t)sEnt[ra + j * 32] * FDIM + c8;
        gB[j] = wdT + ((size_t)e * DIM + n0 + ra + j * 32) * FDIM + c8;
    }
    f16_t* dA = &sA[tid * 8];
    f16_t* dB = &sB[tid * 8];

    f32x4 acc[4][4];
    f32x4 zero = {0.f, 0.f, 0.f, 0.f};
#pragma unroll
    for (int i = 0; i < 4; i++)
#pragma unroll
        for (int j = 0; j < 4; j++) acc[i][j] = zero;

    int wm = (wave & 1) * 64, wn = (wave >> 1) * 64;
    int fm = lane & 15, quad = lane >> 4;

    for (int k0 = 0; k0 < FDIM; k0 += 64) {
#pragma unroll
        for (int j = 0; j < 4; j++) {
            gl2lds16(gA[j] + k0, dA + j * 2048);
            gl2lds16(gB[j] + k0, dB + j * 2048);
        }
        __syncthreads();
#pragma unroll
        for (int ks = 0; ks < 2; ++ks) {
            f16x8 af[4], bf[4];
#pragma unroll
            for (int mi = 0; mi < 4; mi++)
                af[mi] = *(const f16x8*)&sA[(wm + mi * 16 + fm) * 64 +
                                            ((ks * 4 + quad + fm) & 7) * 8];
#pragma unroll
            for (int ni = 0; ni < 4; ni++)
                bf[ni] = *(const f16x8*)&sB[(wn + ni * 16 + fm) * 64 +
                                            ((ks * 4 + quad + fm) & 7) * 8];
#pragma unroll
            for (int mi = 0; mi < 4; mi++)
#pragma unroll
                for (int ni = 0; ni < 4; ni++)
                    acc[mi][ni] = __builtin_amdgcn_mfma_f32_16x16x32_f16(af[mi], bf[ni], acc[mi][ni], 0, 0, 0);
        }
        __syncthreads();
    }
    int crow = quad * 4, ccol = fm;
#pragma unroll
    for (int mi = 0; mi < 4; mi++) {
#pragma unroll
        for (int i = 0; i < 4; i++) {
            int m = wm + mi * 16 + crow + i;
            if (m0 + m < cnt) {
                int ent = sEnt[m];
                float w = topw[ent];
                float* yr = Y + (size_t)ent * DIM + n0 + wn;
#pragma unroll
                for (int ni = 0; ni < 4; ni++)
                    yr[ni * 16 + ccol] = w * acc[mi][ni][i];
            }
        }
    }
}

// ---------------- Combine: out[t] = Y[2t] + Y[2t+1] ----------------
__global__ __launch_bounds__(256) void combine_kernel(
    const float* __restrict__ Y, float* __restrict__ out)
{
    int i = blockIdx.x * 256 + threadIdx.x;
    int t = i >> 8;
    int c = i & 255;
    float4 a = ((const float4*)Y)[(size_t)(2 * t) * 256 + c];
    float4 b = ((const float4*)Y)[(size_t)(2 * t + 1) * 256 + c];
    float4 o;
    o.x = a.x + b.x; o.y = a.y + b.y; o.z = a.z + b.z; o.w = a.w + b.w;
    ((float4*)out)[i] = o;
}

extern "C" void kernel_launch(void* const* d_in, const int* in_sizes, int n_in,
                              void* d_out, int out_size, void* d_ws, size_t ws_size,
                              hipStream_t stream) {
    const float* x  = (const float*)d_in[0];
    const float* wr = (const float*)d_in[1];
    const float* wg = (const float*)d_in[2];
    const float* wu = (const float*)d_in[3];
    const float* wd = (const float*)d_in[4];
    float* out = (float*)d_out;
    char* ws = (char*)d_ws;
    const size_t MB = 1ull << 20;

    int*   counts = (int*)ws;                       // 1 KB
    int*   bucket = (int*)(ws + 1024);              // 128 KB
    float* topw   = (float*)(ws + 160 * 1024);      // 32 KB
    f16_t* xf     = (f16_t*)(ws + 1 * MB);          // 1..9 MB   (dead after gateup)
    f16_t* wgT    = (f16_t*)(ws + 9 * MB);          // 9..41 MB  (dead after gateup)
    f16_t* wuT    = (f16_t*)(ws + 41 * MB);         // 41..73 MB (dead after gateup)
    f16_t* H      = (f16_t*)(ws + 73 * MB);         // 73..105 MB
    f16_t* wdT    = (f16_t*)(ws + 1 * MB);          // alias 1..33 MB
    float* Y      = (float*)(ws + 33 * MB);         // alias 33..65 MB

    hipMemsetAsync(counts, 0, 1024, stream);
    router_kernel<<<256, 256, 0, stream>>>(x, wr, topw, counts, bucket, xf);
    transpose_cvt<<<dim3(256, 16), 256, 0, stream>>>(wg, wu, wgT, wuT, DIM, FDIM, DIM / 128, NEXP);
    gateup_kernel<<<dim3(FDIM / 64, 32, NEXP), 256, 0, stream>>>(xf, wgT, wuT, counts, bucket, H);
    transpose_cvt<<<dim3(256, 8), 256, 0, stream>>>(wd, wd, wdT, wdT, FDIM, DIM, FDIM / 128, NEXP);
    down_kernel<<<dim3(DIM / 128, 32, NEXP), 256, 0, stream>>>(H, wdT, counts, bucket, topw, Y);
    combine_kernel<<<4096, 256, 0, stream>>>(Y, out);
}